// Round 7
// baseline (353.265 us; speedup 1.0000x reference)
//
#include <hip/hip_runtime.h>
#include <hip/hip_bf16.h>

#define N_ROWS 65536
#define NB_CL 512
#define EMB 512

typedef __attribute__((ext_vector_type(8))) short short8;
typedef __attribute__((ext_vector_type(4))) float floatx4;

__device__ __forceinline__ float bf2f(unsigned short u) {
    union { unsigned int i; float f; } v; v.i = ((unsigned int)u) << 16; return v.f;
}
__device__ __forceinline__ unsigned short f2bf(float f) {
    union { float f; unsigned int i; } v; v.f = f;
    unsigned int x = v.i;
    x += ((x >> 16) & 1u) + 0x7FFFu;   // round-to-nearest-even
    return (unsigned short)(x >> 16);
}

// async global->LDS, 16B per lane (m97 pattern; LDS dest = wave-uniform base
// + lane*16 -- layout must be linear in lane order)
__device__ __forceinline__ void gload_lds16(const void* g, void* l) {
    __builtin_amdgcn_global_load_lds(
        (const __attribute__((address_space(1))) unsigned int*)g,
        (__attribute__((address_space(3))) unsigned int*)l,
        16, 0, 0);
}

// ---------------- normalize rows: dst = bf16(3 * row / max(||row||, eps)) ----
__global__ __launch_bounds__(256) void k_normalize(const float* __restrict__ src,
                                                   unsigned short* __restrict__ dst,
                                                   int rows) {
    int gwave = (blockIdx.x * 256 + threadIdx.x) >> 6;
    int lane  = threadIdx.x & 63;
    if (gwave >= rows) return;
    const float4* r = reinterpret_cast<const float4*>(src) + (size_t)gwave * 128;
    float4 a = r[lane];
    float4 b = r[lane + 64];
    float ss = a.x*a.x + a.y*a.y + a.z*a.z + a.w*a.w
             + b.x*b.x + b.y*b.y + b.z*b.z + b.w*b.w;
#pragma unroll
    for (int off = 1; off < 64; off <<= 1) ss += __shfl_xor(ss, off, 64);
    float sc = 3.0f / fmaxf(sqrtf(ss), 1e-12f);
    ushort4 oa, ob;
    oa.x = f2bf(a.x * sc); oa.y = f2bf(a.y * sc); oa.z = f2bf(a.z * sc); oa.w = f2bf(a.w * sc);
    ob.x = f2bf(b.x * sc); ob.y = f2bf(b.y * sc); ob.z = f2bf(b.z * sc); ob.w = f2bf(b.w * sc);
    unsigned short* d = dst + (size_t)gwave * EMB;
    *reinterpret_cast<ushort4*>(d + 4 * lane)       = oa;
    *reinterpret_cast<ushort4*>(d + 256 + 4 * lane) = ob;
}

// ---------------- neighbor dots: c2[i] = Xn_i . Xn_{(i+4) mod N} -------------
__global__ __launch_bounds__(256) void k_neighbor(const unsigned short* __restrict__ Xn,
                                                  float* __restrict__ c2) {
    int i    = (blockIdx.x * 256 + threadIdx.x) >> 6;
    int lane = threadIdx.x & 63;
    int j    = (i + 4) & (N_ROWS - 1);
    uint4 va = *reinterpret_cast<const uint4*>(Xn + (size_t)i * EMB + lane * 8);
    uint4 vb = *reinterpret_cast<const uint4*>(Xn + (size_t)j * EMB + lane * 8);
    const unsigned short* pa = reinterpret_cast<const unsigned short*>(&va);
    const unsigned short* pb = reinterpret_cast<const unsigned short*>(&vb);
    float d = 0.f;
#pragma unroll
    for (int k = 0; k < 8; ++k) d += bf2f(pa[k]) * bf2f(pb[k]);
#pragma unroll
    for (int off = 1; off < 64; off <<= 1) d += __shfl_xor(d, off, 64);
    if (lane == 0) c2[i] = d;
}

// ---------------- fused GEMM + loss --------------------------------------
// Block: 64 rows x 512 classes (full N). 512 thr = 8 waves, wave w owns cols
// [w*64, w*64+64) as 4x4 16x16 frags. S never hits global (except 8 boundary
// rows/block -> side buffers). Virtual row i mixes rows i and i+4 in-register
// via shuffles on the C-layout (row=(lane>>4)*4+reg, col=lane&15):
//   (r&15)<12 : row+4 = same frag, lane+16
//   g==3,mf<3 : row+4 = frag mf+1, lane&15 (g=0, same reg)
//   mf==3,g==3: rows 60-63 -> cross-block, deferred to k_cleanup
__global__ __launch_bounds__(512) void k_fused(const unsigned short* __restrict__ A,
                                               const unsigned short* __restrict__ B,
                                               const int* __restrict__ T,
                                               const float* __restrict__ c2,
                                               float* __restrict__ sideA,
                                               float* __restrict__ sideB,
                                               float* __restrict__ partial) {
    __shared__ __align__(16) unsigned short As[64 * 64];     //  8 KB
    __shared__ __align__(16) unsigned short Bs[512 * 64];    // 64 KB
    __shared__ float part[64 * 8 * 4];                        //  8 KB
    __shared__ float tgt[64 * 3];
    __shared__ float c2l[64];
    __shared__ int   Til[64];
    __shared__ int   Tjl[64];

    int t = threadIdx.x;
    int wave = t >> 6, lane = t & 63;
    int m0 = blockIdx.x << 6;

    floatx4 acc[4][4];
#pragma unroll
    for (int mf = 0; mf < 4; ++mf)
#pragma unroll
        for (int nf = 0; nf < 4; ++nf) acc[mf][nf] = (floatx4){0.f, 0.f, 0.f, 0.f};

    // per-row metadata (consumed after K-loop barriers)
    if (t < 64) {
        int gr = m0 + t;
        c2l[t] = c2[gr];
        Til[t] = T[gr];
        Tjl[t] = T[(gr + 4) & (N_ROWS - 1)];
    }

    int srow = lane >> 3;          // 0..7
    int scol = (lane & 7) << 3;    // 0..56

    for (int k0 = 0; k0 < EMB; k0 += 64) {
        // A: 64x64 tile, wave w stages rows 8w..8w+7
        gload_lds16(A + (size_t)(m0 + wave * 8 + srow) * EMB + k0 + scol, As + wave * 512);
        // B: 512x64 tile, 8 issues/wave
#pragma unroll
        for (int it = 0; it < 8; ++it)
            gload_lds16(B + (size_t)(it * 64 + wave * 8 + srow) * EMB + k0 + scol,
                        Bs + (it * 64 + wave * 8) * 64);
        __syncthreads();
#pragma unroll
        for (int kk = 0; kk < 2; ++kk) {
            int krow = kk * 32 + ((lane >> 4) << 3);
            short8 af[4], bfr[4];
#pragma unroll
            for (int mi = 0; mi < 4; ++mi)
                af[mi] = *reinterpret_cast<const short8*>(
                    &As[(mi * 16 + (lane & 15)) * 64 + krow]);
#pragma unroll
            for (int ni = 0; ni < 4; ++ni)
                bfr[ni] = *reinterpret_cast<const short8*>(
                    &Bs[(wave * 64 + ni * 16 + (lane & 15)) * 64 + krow]);
#pragma unroll
            for (int mi = 0; mi < 4; ++mi)
#pragma unroll
                for (int ni = 0; ni < 4; ++ni)
                    acc[mi][ni] = __builtin_amdgcn_mfma_f32_16x16x32_bf16(
                        af[mi], bfr[ni], acc[mi][ni], 0, 0, 0);
        }
        __syncthreads();
    }

    // ---- boundary S rows to global side buffers (rows 0-3 and 60-63)
    if (lane < 16) {            // rows 0-3: mf=0, g=0 lanes
#pragma unroll
        for (int nf = 0; nf < 4; ++nf)
#pragma unroll
            for (int rg = 0; rg < 4; ++rg)
                sideB[((size_t)blockIdx.x * 4 + rg) * NB_CL + wave * 64 + nf * 16 + lane] =
                    acc[0][nf][rg];
    }
    if (lane >= 48) {           // rows 60-63: mf=3, g=3 lanes
#pragma unroll
        for (int nf = 0; nf < 4; ++nf)
#pragma unroll
            for (int rg = 0; rg < 4; ++rg)
                sideA[((size_t)blockIdx.x * 4 + rg) * NB_CL + wave * 64 + nf * 16 + (lane & 15)] =
                    acc[3][nf][rg];
    }

    // ---- per-(mf,rg) row loss partials over this wave's 64 cols
    int g = lane >> 4;
#pragma unroll
    for (int mf = 0; mf < 4; ++mf) {
#pragma unroll
        for (int rg = 0; rg < 4; ++rg) {
            int r  = mf * 16 + g * 4 + rg;
            int gr = m0 + r;
            unsigned int h = (unsigned int)gr * 2654435769u;
            float lam = (float)h * 2.3283064365386963e-10f;
            float oml = 1.0f - lam;
            float c2i = c2l[r] * (1.0f / 9.0f);
            float r2  = lam * lam + oml * oml + 2.0f * lam * oml * c2i;
            float rinv = rsqrtf(fmaxf(r2, 1e-24f));
            float lrv[4], lvv[4];
#pragma unroll
            for (int nf = 0; nf < 4; ++nf) {
                float s   = acc[mf][nf][rg];
                float s4a = __shfl(acc[mf][nf][rg], (lane + 16) & 63, 64);
                float s4b = __shfl(acc[(mf < 3) ? (mf + 1) : 3][nf][rg], lane & 15, 64);
                float s4  = (g < 3) ? s4a : s4b;     // garbage only for mf==3&&g==3 (excluded)
                lrv[nf] = 2.0f * s;
                lvv[nf] = 2.0f * rinv * (lam * s + oml * s4);
            }
            float mr = fmaxf(fmaxf(lrv[0], lrv[1]), fmaxf(lrv[2], lrv[3]));
            float mv = fmaxf(fmaxf(lvv[0], lvv[1]), fmaxf(lvv[2], lvv[3]));
#pragma unroll
            for (int off = 1; off < 16; off <<= 1) {
                mr = fmaxf(mr, __shfl_xor(mr, off, 64));
                mv = fmaxf(mv, __shfl_xor(mv, off, 64));
            }
            float sr = 0.f, sv = 0.f;
#pragma unroll
            for (int nf = 0; nf < 4; ++nf) {
                sr += __expf(lrv[nf] - mr);
                sv += __expf(lvv[nf] - mv);
                int col = wave * 64 + nf * 16 + (lane & 15);
                if (col == Til[r]) { tgt[r * 3 + 0] = lrv[nf]; tgt[r * 3 + 1] = lvv[nf]; }
                if (col == Tjl[r]) { tgt[r * 3 + 2] = lvv[nf]; }
            }
#pragma unroll
            for (int off = 1; off < 16; off <<= 1) {
                sr += __shfl_xor(sr, off, 64);
                sv += __shfl_xor(sv, off, 64);
            }
            if ((lane & 15) == 0) {
                float* p = &part[(r * 8 + wave) * 4];
                p[0] = mr; p[1] = sr; p[2] = mv; p[3] = sv;
            }
        }
    }
    __syncthreads();

    // ---- wave 0: combine 8 per-wave partials per row, sum block loss
    if (t < 64) {
        int r = t, gr = m0 + r;
        float M = -3.0e38f, Mv = -3.0e38f;
#pragma unroll
        for (int nw = 0; nw < 8; ++nw) {
            M  = fmaxf(M,  part[(r * 8 + nw) * 4 + 0]);
            Mv = fmaxf(Mv, part[(r * 8 + nw) * 4 + 2]);
        }
        float Sr = 0.f, Sv = 0.f;
#pragma unroll
        for (int nw = 0; nw < 8; ++nw) {
            Sr += part[(r * 8 + nw) * 4 + 1] * __expf(part[(r * 8 + nw) * 4 + 0] - M);
            Sv += part[(r * 8 + nw) * 4 + 3] * __expf(part[(r * 8 + nw) * 4 + 2] - Mv);
        }
        float LSEr = M  + __logf(Sr);
        float LSEv = Mv + __logf(Sv);
        unsigned int h = (unsigned int)gr * 2654435769u;
        float lam = (float)h * 2.3283064365386963e-10f;
        float oml = 1.0f - lam;
        float loss = LSEr - tgt[r * 3 + 0];
        if (r < 60)
            loss += lam * (LSEv - tgt[r * 3 + 1]) + oml * (LSEv - tgt[r * 3 + 2]);
#pragma unroll
        for (int off = 1; off < 64; off <<= 1) loss += __shfl_xor(loss, off, 64);
        if (t == 0) partial[blockIdx.x] = loss;
    }
}

// ---------------- deferred boundary virtual rows (4 per fused block) --------
__global__ __launch_bounds__(256) void k_cleanup(const float* __restrict__ sideA,
                                                 const float* __restrict__ sideB,
                                                 const int* __restrict__ T,
                                                 const float* __restrict__ c2,
                                                 float* __restrict__ partial2) {
    __shared__ float red[4];
    int wave = threadIdx.x >> 6, lane = threadIdx.x & 63;
    int q  = blockIdx.x * 4 + wave;          // 0..4095
    int b  = q >> 2, rr = q & 3;
    int i  = b * 64 + 60 + rr;
    const float4* Si = reinterpret_cast<const float4*>(sideA + ((size_t)b * 4 + rr) * NB_CL);
    const float4* Sj = reinterpret_cast<const float4*>(sideB + ((size_t)((b + 1) & 1023) * 4 + rr) * NB_CL);
    float4 a0 = Si[lane], a1 = Si[lane + 64];
    float4 b0 = Sj[lane], b1 = Sj[lane + 64];
    int Ti = T[i], Tj = T[(i + 4) & (N_ROWS - 1)];

    unsigned int h = (unsigned int)i * 2654435769u;
    float lam = (float)h * 2.3283064365386963e-10f;
    float oml = 1.0f - lam;
    float c2i  = c2[i] * (1.0f / 9.0f);
    float r2   = lam * lam + oml * oml + 2.0f * lam * oml * c2i;
    float rinv = rsqrtf(fmaxf(r2, 1e-24f));

    float sa[8] = {a0.x, a0.y, a0.z, a0.w, a1.x, a1.y, a1.z, a1.w};
    float sb[8] = {b0.x, b0.y, b0.z, b0.w, b1.x, b1.y, b1.z, b1.w};
    float lv[8];
#pragma unroll
    for (int k = 0; k < 8; ++k) lv[k] = 2.0f * rinv * (lam * sa[k] + oml * sb[k]);
    float mv = lv[0];
#pragma unroll
    for (int k = 1; k < 8; ++k) mv = fmaxf(mv, lv[k]);
#pragma unroll
    for (int off = 1; off < 64; off <<= 1) mv = fmaxf(mv, __shfl_xor(mv, off, 64));
    float ev = 0.f, gv1 = 0.f, gv2 = 0.f;
#pragma unroll
    for (int k = 0; k < 8; ++k) {
        ev += __expf(lv[k] - mv);
        int col = (k < 4) ? (4 * lane + k) : (256 + 4 * lane + (k - 4));
        if (col == Ti) gv1 = lv[k];
        if (col == Tj) gv2 = lv[k];
    }
#pragma unroll
    for (int off = 1; off < 64; off <<= 1) {
        ev  += __shfl_xor(ev, off, 64);
        gv1 += __shfl_xor(gv1, off, 64);
        gv2 += __shfl_xor(gv2, off, 64);
    }
    if (lane == 0) {
        float LSE = mv + __logf(ev);
        red[wave] = lam * (LSE - gv1) + oml * (LSE - gv2);
    }
    __syncthreads();
    if (threadIdx.x == 0)
        partial2[blockIdx.x] = red[0] + red[1] + red[2] + red[3];
}

// ---------------- final: sum 2048 partials (partial+partial2 contiguous) ----
__global__ __launch_bounds__(256) void k_final(const float* __restrict__ partial,
                                               float* __restrict__ out) {
    __shared__ float red[4];
    float s = 0.f;
    for (int k = threadIdx.x; k < 2048; k += 256) s += partial[k];
#pragma unroll
    for (int off = 1; off < 64; off <<= 1) s += __shfl_xor(s, off, 64);
    int lane = threadIdx.x & 63, wave = threadIdx.x >> 6;
    if (lane == 0) red[wave] = s;
    __syncthreads();
    if (threadIdx.x == 0)
        out[0] = (red[0] + red[1] + red[2] + red[3]) * (1.0f / (2.0f * (float)N_ROWS));
}

extern "C" void kernel_launch(void* const* d_in, const int* in_sizes, int n_in,
                              void* d_out, int out_size, void* d_ws, size_t ws_size,
                              hipStream_t stream) {
    const float* X = (const float*)d_in[0];
    const int*   T = (const int*)d_in[2];
    const float* P = (const float*)d_in[3];

    char* ws = (char*)d_ws;
    unsigned short* Xn = (unsigned short*)(ws);                  // 67,108,864 B
    unsigned short* Pn = (unsigned short*)(ws + 67108864);       //    524,288 B
    float*          c2 = (float*)(ws + 67633152);                //    262,144 B
    float*     partial = (float*)(ws + 67895296);                //      4,096 B
    float*    partial2 = (float*)(ws + 67899392);                //      4,096 B (contiguous with partial)
    float*       sideA = (float*)(ws + 67903488);                //  8,388,608 B (rows 60-63 / block)
    float*       sideB = (float*)(ws + 76292096);                //  8,388,608 B (rows 0-3 / block)
    float*         out = (float*)d_out;

    hipLaunchKernelGGL(k_normalize, dim3(N_ROWS / 4), dim3(256), 0, stream, X, Xn, N_ROWS);
    hipLaunchKernelGGL(k_normalize, dim3(NB_CL / 4), dim3(256), 0, stream, P, Pn, NB_CL);
    hipLaunchKernelGGL(k_neighbor, dim3(N_ROWS / 4), dim3(256), 0, stream, Xn, c2);
    hipLaunchKernelGGL(k_fused, dim3(N_ROWS / 64), dim3(512), 0, stream,
                       Xn, Pn, T, c2, sideA, sideB, partial);
    hipLaunchKernelGGL(k_cleanup, dim3(1024), dim3(256), 0, stream,
                       sideA, sideB, T, c2, partial2);
    hipLaunchKernelGGL(k_final, dim3(1), dim3(256), 0, stream, partial, out);
}

// Round 9
// 325.508 us; speedup vs baseline: 1.0853x; 1.0853x over previous
//
#include <hip/hip_runtime.h>
#include <hip/hip_bf16.h>

#define N_ROWS 65536
#define NB_CL 512
#define EMB 512

typedef __attribute__((ext_vector_type(8))) short short8;
typedef __attribute__((ext_vector_type(4))) float floatx4;

__device__ __forceinline__ float bf2f(unsigned short u) {
    union { unsigned int i; float f; } v; v.i = ((unsigned int)u) << 16; return v.f;
}
__device__ __forceinline__ unsigned short f2bf(float f) {
    union { float f; unsigned int i; } v; v.f = f;
    unsigned int x = v.i;
    x += ((x >> 16) & 1u) + 0x7FFFu;   // round-to-nearest-even
    return (unsigned short)(x >> 16);
}

// ---------------- normalize rows: dst = bf16(3 * row / max(||row||, eps)) ----
__global__ __launch_bounds__(256) void k_normalize(const float* __restrict__ src,
                                                   unsigned short* __restrict__ dst,
                                                   int rows) {
    int gwave = (blockIdx.x * 256 + threadIdx.x) >> 6;
    int lane  = threadIdx.x & 63;
    if (gwave >= rows) return;
    const float4* r = reinterpret_cast<const float4*>(src) + (size_t)gwave * 128;
    float4 a = r[lane];
    float4 b = r[lane + 64];
    float ss = a.x*a.x + a.y*a.y + a.z*a.z + a.w*a.w
             + b.x*b.x + b.y*b.y + b.z*b.z + b.w*b.w;
#pragma unroll
    for (int off = 1; off < 64; off <<= 1) ss += __shfl_xor(ss, off, 64);
    float sc = 3.0f / fmaxf(sqrtf(ss), 1e-12f);
    ushort4 oa, ob;
    oa.x = f2bf(a.x * sc); oa.y = f2bf(a.y * sc); oa.z = f2bf(a.z * sc); oa.w = f2bf(a.w * sc);
    ob.x = f2bf(b.x * sc); ob.y = f2bf(b.y * sc); ob.z = f2bf(b.z * sc); ob.w = f2bf(b.w * sc);
    unsigned short* d = dst + (size_t)gwave * EMB;
    *reinterpret_cast<ushort4*>(d + 4 * lane)       = oa;
    *reinterpret_cast<ushort4*>(d + 256 + 4 * lane) = ob;
}

// ---------------- neighbor dots: c2[i] = Xn_i . Xn_{(i+4) mod N} -------------
__global__ __launch_bounds__(256) void k_neighbor(const unsigned short* __restrict__ Xn,
                                                  float* __restrict__ c2) {
    int i    = (blockIdx.x * 256 + threadIdx.x) >> 6;
    int lane = threadIdx.x & 63;
    int j    = (i + 4) & (N_ROWS - 1);
    uint4 va = *reinterpret_cast<const uint4*>(Xn + (size_t)i * EMB + lane * 8);
    uint4 vb = *reinterpret_cast<const uint4*>(Xn + (size_t)j * EMB + lane * 8);
    const unsigned short* pa = reinterpret_cast<const unsigned short*>(&va);
    const unsigned short* pb = reinterpret_cast<const unsigned short*>(&vb);
    float d = 0.f;
#pragma unroll
    for (int k = 0; k < 8; ++k) d += bf2f(pa[k]) * bf2f(pb[k]);
#pragma unroll
    for (int off = 1; off < 64; off <<= 1) d += __shfl_xor(d, off, 64);
    if (lane == 0) c2[i] = d;
}

// ---------------- fused GEMM + loss --------------------------------------
// R7 rework (R7 counters: MfmaUtil 10%, Occ 21.6%, 1.35e7 bank conflicts,
// 83KB LDS -> 1 block/CU, latency-bound):
//  * Bs LDS staging DELETED -- B (Pn, 0.5MB, L2-resident) fragments read
//    directly global->reg (16 rows x 64B segments per wave-load).
//  * A reg-staged into XOR-swizzled LDS (write slot (t&7)^(tr&7), read slot
//    (ce/8)^(r&7)) -- 16-way conflict -> 2-way (free, m136). gload_lds
//    dropped since swizzle requires reg-staging (m104).
//  * LDS 83 -> ~18 KB -> 4 blocks/CU (32 waves) for latency hiding.
// Epilogue (verified absmax=0 in R7) unchanged.
__global__ __launch_bounds__(512) void k_fused(const unsigned short* __restrict__ A,
                                               const unsigned short* __restrict__ B,
                                               const int* __restrict__ T,
                                               const float* __restrict__ c2,
                                               float* __restrict__ sideA,
                                               float* __restrict__ sideB,
                                               float* __restrict__ partial) {
    __shared__ __align__(16) unsigned short As[64 * 64];      //  8 KB (swizzled)
    __shared__ float part[64 * 8 * 4];                        //  8 KB
    __shared__ float tgt[64 * 3];
    __shared__ float c2l[64];
    __shared__ int   Til[64];
    __shared__ int   Tjl[64];

    int t = threadIdx.x;
    int wave = t >> 6, lane = t & 63;
    int m0 = blockIdx.x << 6;

    floatx4 acc[4][4];
#pragma unroll
    for (int mf = 0; mf < 4; ++mf)
#pragma unroll
        for (int nf = 0; nf < 4; ++nf) acc[mf][nf] = (floatx4){0.f, 0.f, 0.f, 0.f};

    if (t < 64) {
        int gr = m0 + t;
        c2l[t] = c2[gr];
        Til[t] = T[gr];
        Tjl[t] = T[(gr + 4) & (N_ROWS - 1)];
    }

    // A staging: thread t loads row tr=t>>3, cols (t&7)*8..+7 (16B); writes
    // LDS at col-slot (t&7)^(tr&7)  [XOR swizzle, elements *8]
    int tr = t >> 3;
    const unsigned short* Ag = A + (size_t)(m0 + tr) * EMB + ((t & 7) << 3);
    unsigned short* As_w = As + tr * 64 + ((((t & 7) ^ (tr & 7))) << 3);

    int g = lane >> 4;                       // 0..3
    int rlo = lane & 15;                     // fragment row-within-16

    for (int k0 = 0; k0 < EMB; k0 += 64) {
        // B fragments for this k0: both kk halves, global->reg (L2 hit)
        short8 bfr2[2][4];
#pragma unroll
        for (int kk = 0; kk < 2; ++kk)
#pragma unroll
            for (int ni = 0; ni < 4; ++ni) {
                int brow = wave * 64 + ni * 16 + rlo;
                bfr2[kk][ni] = *reinterpret_cast<const short8*>(
                    B + (size_t)brow * EMB + k0 + kk * 32 + (g << 3));
            }
        // A tile: global->reg->swizzled LDS
        short8 av = *reinterpret_cast<const short8*>(Ag + k0);
        *reinterpret_cast<short8*>(As_w) = av;
        __syncthreads();
#pragma unroll
        for (int kk = 0; kk < 2; ++kk) {
            short8 af[4];
#pragma unroll
            for (int mi = 0; mi < 4; ++mi) {
                int ce = kk * 32 + (g << 3);            // col-elements, mult of 8
                int sw = ce ^ ((rlo & 7) << 3);         // read-side XOR swizzle
                af[mi] = *reinterpret_cast<const short8*>(
                    &As[(mi * 16 + rlo) * 64 + sw]);
            }
#pragma unroll
            for (int mi = 0; mi < 4; ++mi)
#pragma unroll
                for (int ni = 0; ni < 4; ++ni)
                    acc[mi][ni] = __builtin_amdgcn_mfma_f32_16x16x32_bf16(
                        af[mi], bfr2[kk][ni], acc[mi][ni], 0, 0, 0);
        }
        __syncthreads();
    }

    // ---- boundary S rows to global side buffers (rows 0-3 and 60-63)
    if (lane < 16) {            // rows 0-3: mf=0, g=0 lanes
#pragma unroll
        for (int nf = 0; nf < 4; ++nf)
#pragma unroll
            for (int rg = 0; rg < 4; ++rg)
                sideB[((size_t)blockIdx.x * 4 + rg) * NB_CL + wave * 64 + nf * 16 + lane] =
                    acc[0][nf][rg];
    }
    if (lane >= 48) {           // rows 60-63: mf=3, g=3 lanes
#pragma unroll
        for (int nf = 0; nf < 4; ++nf)
#pragma unroll
            for (int rg = 0; rg < 4; ++rg)
                sideA[((size_t)blockIdx.x * 4 + rg) * NB_CL + wave * 64 + nf * 16 + (lane & 15)] =
                    acc[3][nf][rg];
    }

    // ---- per-(mf,rg) row loss partials over this wave's 64 cols
#pragma unroll
    for (int mf = 0; mf < 4; ++mf) {
#pragma unroll
        for (int rg = 0; rg < 4; ++rg) {
            int r  = mf * 16 + g * 4 + rg;
            int gr = m0 + r;
            unsigned int h = (unsigned int)gr * 2654435769u;
            float lam = (float)h * 2.3283064365386963e-10f;
            float oml = 1.0f - lam;
            float c2i = c2l[r] * (1.0f / 9.0f);
            float r2  = lam * lam + oml * oml + 2.0f * lam * oml * c2i;
            float rinv = rsqrtf(fmaxf(r2, 1e-24f));
            float lrv[4], lvv[4];
#pragma unroll
            for (int nf = 0; nf < 4; ++nf) {
                float s   = acc[mf][nf][rg];
                float s4a = __shfl(acc[mf][nf][rg], (lane + 16) & 63, 64);
                float s4b = __shfl(acc[(mf < 3) ? (mf + 1) : 3][nf][rg], lane & 15, 64);
                float s4  = (g < 3) ? s4a : s4b;     // garbage only for mf==3&&g==3 (excluded)
                lrv[nf] = 2.0f * s;
                lvv[nf] = 2.0f * rinv * (lam * s + oml * s4);
            }
            float mr = fmaxf(fmaxf(lrv[0], lrv[1]), fmaxf(lrv[2], lrv[3]));
            float mv = fmaxf(fmaxf(lvv[0], lvv[1]), fmaxf(lvv[2], lvv[3]));
#pragma unroll
            for (int off = 1; off < 16; off <<= 1) {
                mr = fmaxf(mr, __shfl_xor(mr, off, 64));
                mv = fmaxf(mv, __shfl_xor(mv, off, 64));
            }
            float sr = 0.f, sv = 0.f;
#pragma unroll
            for (int nf = 0; nf < 4; ++nf) {
                sr += __expf(lrv[nf] - mr);
                sv += __expf(lvv[nf] - mv);
                int col = wave * 64 + nf * 16 + (lane & 15);
                if (col == Til[r]) { tgt[r * 3 + 0] = lrv[nf]; tgt[r * 3 + 1] = lvv[nf]; }
                if (col == Tjl[r]) { tgt[r * 3 + 2] = lvv[nf]; }
            }
#pragma unroll
            for (int off = 1; off < 16; off <<= 1) {
                sr += __shfl_xor(sr, off, 64);
                sv += __shfl_xor(sv, off, 64);
            }
            if ((lane & 15) == 0) {
                float* p = &part[(r * 8 + wave) * 4];
                p[0] = mr; p[1] = sr; p[2] = mv; p[3] = sv;
            }
        }
    }
    __syncthreads();

    // ---- wave 0: combine 8 per-wave partials per row, sum block loss
    if (t < 64) {
        int r = t, gr = m0 + r;
        float M = -3.0e38f, Mv = -3.0e38f;
#pragma unroll
        for (int nw = 0; nw < 8; ++nw) {
            M  = fmaxf(M,  part[(r * 8 + nw) * 4 + 0]);
            Mv = fmaxf(Mv, part[(r * 8 + nw) * 4 + 2]);
        }
        float Sr = 0.f, Sv = 0.f;
#pragma unroll
        for (int nw = 0; nw < 8; ++nw) {
            Sr += part[(r * 8 + nw) * 4 + 1] * __expf(part[(r * 8 + nw) * 4 + 0] - M);
            Sv += part[(r * 8 + nw) * 4 + 3] * __expf(part[(r * 8 + nw) * 4 + 2] - Mv);
        }
        float LSEr = M  + __logf(Sr);
        float LSEv = Mv + __logf(Sv);
        unsigned int h = (unsigned int)gr * 2654435769u;
        float lam = (float)h * 2.3283064365386963e-10f;
        float oml = 1.0f - lam;
        float loss = LSEr - tgt[r * 3 + 0];
        if (r < 60)
            loss += lam * (LSEv - tgt[r * 3 + 1]) + oml * (LSEv - tgt[r * 3 + 2]);
#pragma unroll
        for (int off = 1; off < 64; off <<= 1) loss += __shfl_xor(loss, off, 64);
        if (t == 0) partial[blockIdx.x] = loss;
    }
}

// ---------------- deferred boundary virtual rows (4 per fused block) --------
__global__ __launch_bounds__(256) void k_cleanup(const float* __restrict__ sideA,
                                                 const float* __restrict__ sideB,
                                                 const int* __restrict__ T,
                                                 const float* __restrict__ c2,
                                                 float* __restrict__ partial2) {
    __shared__ float red[4];
    int wave = threadIdx.x >> 6, lane = threadIdx.x & 63;
    int q  = blockIdx.x * 4 + wave;          // 0..4095
    int b  = q >> 2, rr = q & 3;
    int i  = b * 64 + 60 + rr;
    const float4* Si = reinterpret_cast<const float4*>(sideA + ((size_t)b * 4 + rr) * NB_CL);
    const float4* Sj = reinterpret_cast<const float4*>(sideB + ((size_t)((b + 1) & 1023) * 4 + rr) * NB_CL);
    float4 a0 = Si[lane], a1 = Si[lane + 64];
    float4 b0 = Sj[lane], b1 = Sj[lane + 64];
    int Ti = T[i], Tj = T[(i + 4) & (N_ROWS - 1)];

    unsigned int h = (unsigned int)i * 2654435769u;
    float lam = (float)h * 2.3283064365386963e-10f;
    float oml = 1.0f - lam;
    float c2i  = c2[i] * (1.0f / 9.0f);
    float r2   = lam * lam + oml * oml + 2.0f * lam * oml * c2i;
    float rinv = rsqrtf(fmaxf(r2, 1e-24f));

    float sa[8] = {a0.x, a0.y, a0.z, a0.w, a1.x, a1.y, a1.z, a1.w};
    float sb[8] = {b0.x, b0.y, b0.z, b0.w, b1.x, b1.y, b1.z, b1.w};
    float lv[8];
#pragma unroll
    for (int k = 0; k < 8; ++k) lv[k] = 2.0f * rinv * (lam * sa[k] + oml * sb[k]);
    float mv = lv[0];
#pragma unroll
    for (int k = 1; k < 8; ++k) mv = fmaxf(mv, lv[k]);
#pragma unroll
    for (int off = 1; off < 64; off <<= 1) mv = fmaxf(mv, __shfl_xor(mv, off, 64));
    float ev = 0.f, gv1 = 0.f, gv2 = 0.f;
#pragma unroll
    for (int k = 0; k < 8; ++k) {
        ev += __expf(lv[k] - mv);
        int col = (k < 4) ? (4 * lane + k) : (256 + 4 * lane + (k - 4));
        if (col == Ti) gv1 = lv[k];
        if (col == Tj) gv2 = lv[k];
    }
#pragma unroll
    for (int off = 1; off < 64; off <<= 1) {
        ev  += __shfl_xor(ev, off, 64);
        gv1 += __shfl_xor(gv1, off, 64);
        gv2 += __shfl_xor(gv2, off, 64);
    }
    if (lane == 0) {
        float LSE = mv + __logf(ev);
        red[wave] = lam * (LSE - gv1) + oml * (LSE - gv2);
    }
    __syncthreads();
    if (threadIdx.x == 0)
        partial2[blockIdx.x] = red[0] + red[1] + red[2] + red[3];
}

// ---------------- final: sum 2048 partials (partial+partial2 contiguous) ----
__global__ __launch_bounds__(256) void k_final(const float* __restrict__ partial,
                                               float* __restrict__ out) {
    __shared__ float red[4];
    float s = 0.f;
    for (int k = threadIdx.x; k < 2048; k += 256) s += partial[k];
#pragma unroll
    for (int off = 1; off < 64; off <<= 1) s += __shfl_xor(s, off, 64);
    int lane = threadIdx.x & 63, wave = threadIdx.x >> 6;
    if (lane == 0) red[wave] = s;
    __syncthreads();
    if (threadIdx.x == 0)
        out[0] = (red[0] + red[1] + red[2] + red[3]) * (1.0f / (2.0f * (float)N_ROWS));
}

extern "C" void kernel_launch(void* const* d_in, const int* in_sizes, int n_in,
                              void* d_out, int out_size, void* d_ws, size_t ws_size,
                              hipStream_t stream) {
    const float* X = (const float*)d_in[0];
    const int*   T = (const int*)d_in[2];
    const float* P = (const float*)d_in[3];

    char* ws = (char*)d_ws;
    unsigned short* Xn = (unsigned short*)(ws);                  // 67,108,864 B
    unsigned short* Pn = (unsigned short*)(ws + 67108864);       //    524,288 B
    float*          c2 = (float*)(ws + 67633152);                //    262,144 B
    float*     partial = (float*)(ws + 67895296);                //      4,096 B
    float*    partial2 = (float*)(ws + 67899392);                //      4,096 B (contiguous with partial)
    float*       sideA = (float*)(ws + 67903488);                //  8,388,608 B (rows 60-63 / block)
    float*       sideB = (float*)(ws + 76292096);                //  8,388,608 B (rows 0-3 / block)
    float*         out = (float*)d_out;

    hipLaunchKernelGGL(k_normalize, dim3(N_ROWS / 4), dim3(256), 0, stream, X, Xn, N_ROWS);
    hipLaunchKernelGGL(k_normalize, dim3(NB_CL / 4), dim3(256), 0, stream, P, Pn, NB_CL);
    hipLaunchKernelGGL(k_neighbor, dim3(N_ROWS / 4), dim3(256), 0, stream, Xn, c2);
    hipLaunchKernelGGL(k_fused, dim3(N_ROWS / 64), dim3(512), 0, stream,
                       Xn, Pn, T, c2, sideA, sideB, partial);
    hipLaunchKernelGGL(k_cleanup, dim3(1024), dim3(256), 0, stream,
                       sideA, sideB, T, c2, partial2);
    hipLaunchKernelGGL(k_final, dim3(1), dim3(256), 0, stream, partial, out);
}